// Round 1
// baseline (114.717 us; speedup 1.0000x reference)
//
#include <hip/hip_runtime.h>

// Problem constants
static constexpr int NQ    = 12;
static constexpr int DEPTH = 4;
static constexpr int LAT   = 512;
static constexpr int FAST  = DEPTH * NQ;   // 48
static constexpr float DECAY = 0.9f;
static constexpr int P     = 68;           // row pitch (floats): 272 B, 16B-aligned

using v2f = __attribute__((ext_vector_type(2))) float;

// r15 KEY CHANGE: ONE WAVE = ONE batch element, 2048 blocks.
// Previous version (2 elem/wave, 35.8KB LDS) was capped at 4 waves/CU =
// 1 wave/SIMD (grid 1024 = 4 blocks/CU; LDS also capped at 4) -> VALUBusy 32%,
// Occupancy 9.7%: pure latency-bound, nothing to hide LDS round trips.
// Single-element waves halve LDS to ~17.8KB -> 8 blocks/CU resident, and the
// grid (2048 = 8/CU) exactly fills it: 2 waves/SIMD. Intra-wave A/B ILP is
// replaced by TLP (sibling wave issues butterflies while this wave waits on
// lgkmcnt for transpose reads).
//
// L orientation: i = (lane<<6) | r (wires 0..5 lane bits, 6..11 reg bits); T swaps.
// Layer = RY(12) o CNOT-chain(0..10); sigma^-1: bit_p = j_p ^ j_{p+1}.
// Pass 1: b128 row-writes + sigma-and-transpose-folded b32 reads (verified).
// Pass 2: b32 scatter-writes + b128 row-reads (verified r13).

template<int S, int B>
__device__ __forceinline__ void bfly_half(float (&v)[64], float c, float s) {
    v2f c2 = {c, c}, s2 = {s, s};
    #pragma unroll
    for (int r0 = B; r0 < B + 32; r0 += 2) {
        if ((r0 & S) == 0) {
            v2f a = {v[r0],     v[r0 + 1]};
            v2f b = {v[r0 + S], v[r0 + S + 1]};
            v2f na = c2 * a - s2 * b;
            v2f nb = s2 * a + c2 * b;
            v[r0]     = na.x;  v[r0 + 1]     = na.y;
            v[r0 + S] = nb.x;  v[r0 + S + 1] = nb.y;
        }
    }
}

template<int B>
__device__ __forceinline__ void bfly1_half(float (&v)[64], float c, float s) {
    v2f cs = {c, s}, nsc = {-s, c};
    #pragma unroll
    for (int r0 = B; r0 < B + 32; r0 += 2) {
        float a = v[r0], b = v[r0 + 1];
        v2f aa = {a, a}, bb = {b, b};
        v2f res = cs * aa + nsc * bb;   // (c*a - s*b, s*a + c*b)
        v[r0]     = res.x;
        v[r0 + 1] = res.y;
    }
}

template<int B>
__device__ __forceinline__ void ry5_half(float (&v)[64], const v2f* cs) {
    bfly_half<16, B>(v, cs[0].x, cs[0].y);
    bfly_half<8,  B>(v, cs[1].x, cs[1].y);
    bfly_half<4,  B>(v, cs[2].x, cs[2].y);
    bfly_half<2,  B>(v, cs[3].x, cs[3].y);
    bfly1_half<B>(v, cs[4].x, cs[4].y);
}

__device__ __forceinline__ void bfly32(float (&v)[64], float c, float s) {
    v2f c2 = {c, c}, s2 = {s, s};
    #pragma unroll
    for (int r0 = 0; r0 < 32; r0 += 2) {
        v2f a = {v[r0],      v[r0 + 1]};
        v2f b = {v[r0 + 32], v[r0 + 33]};
        v2f na = c2 * a - s2 * b;
        v2f nb = s2 * a + c2 * b;
        v[r0]      = na.x;  v[r0 + 1]  = na.y;
        v[r0 + 32] = nb.x;  v[r0 + 33] = nb.y;
    }
}

// full 6-wire butterfly block for one orientation (wires cs[0..5], cs[0]=stride32)
__device__ __forceinline__ void ry6(float (&v)[64], const v2f* cs) {
    ry5_half<0>(v, cs + 1);
    ry5_half<32>(v, cs + 1);
    bfly32(v, cs[0].x, cs[0].y);   // stride-32 wire last (commutes)
}

// pass-1 pieces (verified r13)
__device__ __forceinline__ void p1w(const float (&v)[64], float* X, int lane) {
    #pragma unroll
    for (int k = 0; k < 16; k++)
        *(float4*)&X[lane * P + 4 * k] =
            (float4){v[4 * k], v[4 * k + 1], v[4 * k + 2], v[4 * k + 3]};
}
__device__ __forceinline__ void p1r(float (&v)[64], const float* X, int A0, int A1) {
    #pragma unroll
    for (int r = 0; r < 64; r++) {
        const int g = r ^ (r >> 1);                 // compile-time imm offset
        v[r] = X[g * P + ((r & 1) ? A1 : A0)];
    }
}
// pass-2 pieces (verified r13)
__device__ __forceinline__ void p2w(const float (&v)[64], float* X, int lane) {
    #pragma unroll
    for (int q = 0; q < 64; q++) X[q * P + lane] = v[q];   // addr = lane*4 + imm
}
__device__ __forceinline__ void p2r(float (&v)[64], const float* X, int lane) {
    #pragma unroll
    for (int k = 0; k < 16; k++) {
        float4 t = *(const float4*)&X[lane * P + 4 * k];
        v[4 * k]     = t.x;  v[4 * k + 1] = t.y;
        v[4 * k + 2] = t.z;  v[4 * k + 3] = t.w;
    }
}

// closed-form product state from the 12 initial RYs (verified r2-r13)
__device__ __forceinline__ void init_state(float (&v)[64], const float (&xa)[NQ], int lane) {
    float g0[NQ], g1[NQ];
    #pragma unroll
    for (int w = 0; w < NQ; w++) {
        float hh = 0.5f * xa[w];
        float c = __cosf(hh), s = __sinf(hh);
        g0[w] = (c - s) * 0.70710678118654752f;
        g1[w] = (c + s) * 0.70710678118654752f;
    }
    float L = 1.0f;
    #pragma unroll
    for (int w = 0; w < 6; w++)
        L *= ((lane >> (5 - w)) & 1) ? g1[w] : g0[w];
    v[0] = L;
    #pragma unroll
    for (int w = 6; w < NQ; w++) {
        const int S = 1 << (11 - w);
        #pragma unroll
        for (int r = 0; r < 64; r += 2 * S) {
            v[r + S] = v[r] * g1[w];
            v[r]     = v[r] * g0[w];
        }
    }
}

__global__ __launch_bounds__(64, 1)
void fwp_kernel(const float* __restrict__ x_t,
                const float* __restrict__ fast_prev,
                const float* __restrict__ W_enc,
                const float* __restrict__ b_enc,
                const float* __restrict__ W_upd,
                const float* __restrict__ b_upd,
                const float* __restrict__ W_ro,
                const float* __restrict__ b_ro,
                float* __restrict__ out_y,
                float* __restrict__ out_fast) {
    const int lane = threadIdx.x;          // block = one wave
    const int e    = blockIdx.x;           // ONE element per wave

    __shared__ __align__(16) float X[64 * P];    // 17408 B
    __shared__ __align__(8)  v2f   cs[FAST];     // 384 B

    float* lat = X;   // latent carved from circuit buffer (dead later)

    // ---- x row (wave-uniform scalar loads, verified r7) ----
    float xa[NQ];
    #pragma unroll
    for (int k = 0; k < NQ; k++) xa[k] = x_t[e * NQ + k];

    // ---- Phase A: lane owns latents j = 8*lane..8*lane+7 (verified r13) ----
    {
        const float4* we = (const float4*)(W_enc + lane * 8 * NQ);  // 8 rows, 384 B
        float4 be0 = *(const float4*)&b_enc[8 * lane];
        float4 be1 = *(const float4*)&b_enc[8 * lane + 4];
        float be[8] = {be0.x, be0.y, be0.z, be0.w, be1.x, be1.y, be1.z, be1.w};
        float l[8];
        #pragma unroll
        for (int t = 0; t < 8; t++) {
            float4 a0 = we[3 * t], a1 = we[3 * t + 1], a2 = we[3 * t + 2];
            float s = be[t]
                + a0.x * xa[0] + a0.y * xa[1] + a0.z * xa[2]  + a0.w * xa[3]
                + a1.x * xa[4] + a1.y * xa[5] + a1.z * xa[6]  + a1.w * xa[7]
                + a2.x * xa[8] + a2.y * xa[9] + a2.z * xa[10] + a2.w * xa[11];
            l[t] = tanhf(s);
        }
        *(float4*)&lat[8 * lane]     = (float4){l[0], l[1], l[2], l[3]};
        *(float4*)&lat[8 * lane + 4] = (float4){l[4], l[5], l[6], l[7]};
    }

    // ---- Phase B: 48 angles; W_upd row loaded once per wave ----
    if (lane < FAST) {
        const float4* wr = (const float4*)(W_upd + lane * LAT);
        const float4* la = (const float4*)(lat);
        float s = b_upd[lane];
        #pragma unroll 8
        for (int j = 0; j < LAT / 4; j++) {
            float4 w4 = wr[j];
            float4 a4 = la[j];   // uniform -> broadcast
            s += w4.x * a4.x + w4.y * a4.y + w4.z * a4.z + w4.w * a4.w;
        }
        float ang = DECAY * fast_prev[e * FAST + lane] + s;
        out_fast[e * FAST + lane] = ang;
        cs[lane] = (v2f){__cosf(0.5f * ang), __sinf(0.5f * ang)};
    }

    // ---- product state ----
    float v[64];
    init_state(v, xa, lane);

    const int A0 = ((lane ^ (lane >> 1)) & 31) | (lane & 32);
    const int A1 = A0 ^ 32;

    // ---- 4 layers; latency hidden by sibling wave (2 waves/SIMD) ----
    #pragma unroll 1
    for (int layer = 0; layer < DEPTH; layer++) {
        v2f c[NQ];
        #pragma unroll
        for (int w = 0; w < NQ; w++) c[w] = cs[layer * NQ + w];

        // -------- pass 1 (sigma + L->T) --------
        p1w(v, X, lane);
        p1r(v, X, A0, A1);
        ry6(v, c);               // fine-grained lgkmcnt: first half starts early

        // -------- pass 2 (transpose back) --------
        p2w(v, X, lane);
        p2r(v, X, lane);
        ry6(v, c + 6);
    }

    // ---- Z expectations folded into readout (verified r9) ----
    float wro[NQ];
    #pragma unroll
    for (int w = 0; w < NQ; w++) wro[w] = W_ro[w];
    float sl = 0.0f;
    #pragma unroll
    for (int w = 0; w < 6; w++)
        sl += ((lane >> (5 - w)) & 1) ? -wro[w] : wro[w];

    float tot = 0.0f, pw[6] = {0, 0, 0, 0, 0, 0};
    #pragma unroll
    for (int r = 0; r < 64; r++) {
        float p = v[r] * v[r];
        tot += p;
        pw[0] += (r & 32) ? -p : p;
        pw[1] += (r & 16) ? -p : p;
        pw[2] += (r & 8)  ? -p : p;
        pw[3] += (r & 4)  ? -p : p;
        pw[4] += (r & 2)  ? -p : p;
        pw[5] += (r & 1)  ? -p : p;
    }
    float y = sl * tot;
    #pragma unroll
    for (int k = 0; k < 6; k++) y += wro[6 + k] * pw[k];
    #pragma unroll
    for (int m = 32; m >= 1; m >>= 1) y += __shfl_xor(y, m, 64);
    if (lane == 0) out_y[e] = y + b_ro[0];
}

extern "C" void kernel_launch(void* const* d_in, const int* in_sizes, int n_in,
                              void* d_out, int out_size, void* d_ws, size_t ws_size,
                              hipStream_t stream) {
    const float* x_t       = (const float*)d_in[0];
    const float* fast_prev = (const float*)d_in[1];
    const float* W_enc     = (const float*)d_in[2];
    const float* b_enc     = (const float*)d_in[3];
    const float* W_upd     = (const float*)d_in[4];
    const float* b_upd     = (const float*)d_in[5];
    const float* W_ro      = (const float*)d_in[6];
    const float* b_ro      = (const float*)d_in[7];
    float* out = (float*)d_out;

    // 2048 blocks x 1 wave, 1 batch element per wave -> 8 resident waves/CU
    fwp_kernel<<<2048, 64, 0, stream>>>(x_t, fast_prev, W_enc, b_enc,
                                        W_upd, b_upd, W_ro, b_ro,
                                        out /*y*/, out + 2048 /*fast_next*/);
}